// Round 11
// baseline (215.271 us; speedup 1.0000x reference)
//
#include <hip/hip_runtime.h>

typedef float f4 __attribute__((ext_vector_type(4)));
typedef int i4 __attribute__((ext_vector_type(4)));

// ---------------------------------------------------------------------------
// R11: sequential-front tile kernel, TWO consecutive 64-row tiles per block.
// Halves the per-block mapping scans and, more importantly, batches both
// tiles' HBM reads into one 16 KB/wave speculative read run issued BEFORE the
// scan (R10's overlap trick), followed by two back-to-back 8.25 KB write
// runs -- fewer DRAM read/write turnarounds per byte. Consecutive blocks
// still cover consecutive 66 KB output windows (compact sliding front).
// Blocks tau >= nb2 handle ragged tails (no-op for uniform lengths).
// ---------------------------------------------------------------------------
__global__ __launch_bounds__(256) void emb_kernel(const float* __restrict__ x,
                                                  const int* __restrict__ lengths,
                                                  float* __restrict__ out,
                                                  int n_seg, int maxt, int nb2) {
    __shared__ alignas(16) float lt[4 * 2064];   // 33 KB: 16-row buffer per wave
    __shared__ int sw[4];                         // cross-wave scan partials
    __shared__ int sres[8];                       // off,L,tloc,found x2 tiles
    const int tid = threadIdx.x;
    const int lane = tid & 63, wave = tid >> 6;
    const int tau = blockIdx.x;

    if (tau < nb2) {
        const int tau0 = 2 * tau, tau1 = 2 * tau + 1;
        const bool has1 = (tau1 < maxt);
        if (tid == 0) { sres[3] = 0; sres[7] = 0; }

        // ---- lengths loads FIRST, so the scan waits only on these ----
        int l[8];
        const int i0 = tid * 8;
        if (i0 + 8 <= n_seg) {
            const i4* lp = (const i4*)(lengths + i0);
            const i4 u0 = lp[0], u1 = lp[1];
            l[0] = u0.x; l[1] = u0.y; l[2] = u0.z; l[3] = u0.w;
            l[4] = u1.x; l[5] = u1.y; l[6] = u1.z; l[7] = u1.w;
        } else {
            #pragma unroll
            for (int j = 0; j < 8; ++j) l[j] = (i0 + j < n_seg) ? lengths[i0 + j] : 0;
        }

        // ---- speculative x loads for BOTH tiles (uniform-mapping guess) ----
        f4 a[8], b[8];
        {
            const f4* ga = (const f4*)(x + (size_t)(64 * tau0 + 16 * wave) * 128);
            #pragma unroll
            for (int p = 0; p < 8; ++p) a[p] = ga[lane + 64 * p];
        }
        if (has1) {
            const f4* gb = (const f4*)(x + (size_t)(64 * tau1 + 16 * wave) * 128);
            #pragma unroll
            for (int p = 0; p < 8; ++p) b[p] = gb[lane + 64 * p];
        }
        __syncthreads();                          // sres init visible

        // ---- chunked block-wide double scan locating tau0 and tau1 ----
        int carry_rows = 0, carry_tiles = 0;
        for (int base = 0; base < n_seg; base += 2048) {
            if (base > 0) {
                const int ii = base + tid * 8;
                #pragma unroll
                for (int j = 0; j < 8; ++j) l[j] = (ii + j < n_seg) ? lengths[ii + j] : 0;
            }
            const int th_rows = l[0]+l[1]+l[2]+l[3]+l[4]+l[5]+l[6]+l[7];
            int incl = th_rows;
            #pragma unroll
            for (int d = 1; d < 64; d <<= 1) { int u = __shfl_up(incl, d, 64); if (lane >= d) incl += u; }
            if (lane == 63) sw[wave] = incl;
            __syncthreads();
            const int w0 = sw[0], w1 = sw[1], w2 = sw[2], w3 = sw[3];
            __syncthreads();
            const int wbase = (wave > 0 ? w0 : 0) + (wave > 1 ? w1 : 0) + (wave > 2 ? w2 : 0);
            const int rows_total = w0 + w1 + w2 + w3;

            int run = carry_rows + wbase + incl - th_rows;
            int offj[8], f[8]; int th_tiles = 0;
            #pragma unroll
            for (int j = 0; j < 8; ++j) {
                offj[j] = run; run += l[j];
                f[j] = ((offj[j] & 15) == 0) ? (l[j] >> 6) : 0;
                th_tiles += f[j];
            }
            int tincl = th_tiles;
            #pragma unroll
            for (int d = 1; d < 64; d <<= 1) { int u = __shfl_up(tincl, d, 64); if (lane >= d) tincl += u; }
            if (lane == 63) sw[wave] = tincl;
            __syncthreads();
            const int t0 = sw[0], t1 = sw[1], t2 = sw[2], t3 = sw[3];
            __syncthreads();
            const int tbase = (wave > 0 ? t0 : 0) + (wave > 1 ? t1 : 0) + (wave > 2 ? t2 : 0);
            const int tiles_total = t0 + t1 + t2 + t3;

            const int tstart = carry_tiles + tbase + tincl - th_tiles;
            const int rel0 = tau0 - tstart;
            const int rel1 = tau1 - tstart;
            if ((rel0 >= 0 && rel0 < th_tiles) || (rel1 >= 0 && rel1 < th_tiles)) {
                int cum = 0;
                #pragma unroll
                for (int j = 0; j < 8; ++j) {
                    if (rel0 >= cum && rel0 < cum + f[j]) {
                        sres[0] = offj[j]; sres[1] = l[j]; sres[2] = rel0 - cum; sres[3] = 1;
                    }
                    if (rel1 >= cum && rel1 < cum + f[j]) {
                        sres[4] = offj[j]; sres[5] = l[j]; sres[6] = rel1 - cum; sres[7] = 1;
                    }
                    cum += f[j];
                }
            }
            carry_rows += rows_total; carry_tiles += tiles_total;
            __syncthreads();
            if (sres[3] && (sres[7] || !has1)) break;   // uniform read-after-sync
        }

        float* __restrict__ lb = lt + wave * 2064;

        // ---- tile A ----
        if (sres[3]) {
            const int off = sres[0], L = sres[1], tloc = sres[2];
            const int gr = off + 64 * tloc;
            if (gr != 64 * tau0) {                 // ragged: spec wrong, reload
                const f4* src2 = (const f4*)(x + (size_t)(gr + 16 * wave) * 128);
                #pragma unroll
                for (int p = 0; p < 8; ++p) a[p] = src2[lane + 64 * p];
            }
            const float invL = 1.0f / (float)L;
            const int r0 = 64 * tloc + 16 * wave;
            #pragma unroll
            for (int p = 0; p < 8; ++p) {
                const int q = lane + 64 * p;
                float* d = &lb[(q >> 5) * 129 + 1 + ((q & 31) << 2)];
                d[0] = a[p].x; d[1] = a[p].y; d[2] = a[p].z; d[3] = a[p].w;
            }
            if (lane < 16) lb[lane * 129] = (float)(r0 + lane + 1) * invL;
            const f4* __restrict__ l4 = (const f4*)lb;
            f4* __restrict__ o4 = (f4*)(out + ((size_t)off + r0) * 129);
            #pragma unroll
            for (int p = 0; p < 8; ++p) o4[lane + 64 * p] = l4[lane + 64 * p];
            if (lane < 4) o4[512 + lane] = l4[512 + lane];
        }

        // ---- tile B ----
        if (has1 && sres[7]) {
            const int off = sres[4], L = sres[5], tloc = sres[6];
            const int gr = off + 64 * tloc;
            if (gr != 64 * tau1) {
                const f4* src2 = (const f4*)(x + (size_t)(gr + 16 * wave) * 128);
                #pragma unroll
                for (int p = 0; p < 8; ++p) b[p] = src2[lane + 64 * p];
            }
            const float invL = 1.0f / (float)L;
            const int r0 = 64 * tloc + 16 * wave;
            #pragma unroll
            for (int p = 0; p < 8; ++p) {
                const int q = lane + 64 * p;
                float* d = &lb[(q >> 5) * 129 + 1 + ((q & 31) << 2)];
                d[0] = b[p].x; d[1] = b[p].y; d[2] = b[p].z; d[3] = b[p].w;
            }
            if (lane < 16) lb[lane * 129] = (float)(r0 + lane + 1) * invL;
            const f4* __restrict__ l4 = (const f4*)lb;
            f4* __restrict__ o4 = (f4*)(out + ((size_t)off + r0) * 129);
            #pragma unroll
            for (int p = 0; p < 8; ++p) o4[lane + 64 * p] = l4[lane + 64 * p];
            if (lane < 4) o4[512 + lane] = l4[512 + lane];
        }
    } else {
        // ---- ragged tail / unaligned-segment fallback (no-op when uniform) ----
        const int s = tau - nb2;
        if (s >= n_seg) return;
        int partial = 0;
        for (int i = tid; i < s; i += 256) partial += lengths[i];
        #pragma unroll
        for (int d = 32; d > 0; d >>= 1) partial += __shfl_xor(partial, d, 64);
        if (lane == 0) sw[wave] = partial;
        __syncthreads();
        const int off = sw[0] + sw[1] + sw[2] + sw[3];
        const int L = lengths[s];
        if (L <= 0) return;
        const float invL = 1.0f / (float)L;
        const float* __restrict__ xs = x + (size_t)off * 128;
        float* __restrict__ os = out + (size_t)off * 129;
        const int f = ((off & 15) == 0) ? (L >> 6) : 0;
        const int E = L * 129;
        for (int e = f * 64 * 129 + tid; e < E; e += 256) {
            const int row = e / 129;
            const int c = e - row * 129;
            os[e] = (c == 0) ? (float)(row + 1) * invL
                             : xs[(size_t)row * 128 + (c - 1)];
        }
    }
}

extern "C" void kernel_launch(void* const* d_in, const int* in_sizes, int n_in,
                              void* d_out, int out_size, void* d_ws, size_t ws_size,
                              hipStream_t stream) {
    const float* x = (const float*)d_in[0];
    const int* lengths = (const int*)d_in[1];
    const int n_seg = in_sizes[1];
    const int rows = in_sizes[0] / 128;
    const int maxt = rows / 64;
    const int nb2 = (maxt + 1) / 2;

    emb_kernel<<<nb2 + n_seg, 256, 0, stream>>>(x, lengths, (float*)d_out,
                                                n_seg, maxt, nb2);
}

// Round 12
// 206.512 us; speedup vs baseline: 1.0424x; 1.0424x over previous
//
#include <hip/hip_runtime.h>

typedef float f4 __attribute__((ext_vector_type(4)));
typedef int i4 __attribute__((ext_vector_type(4)));

// ---------------------------------------------------------------------------
// R12: R10's sequential-front fused-scan tile kernel (199 us), single change:
// LDS footprint halved (33 -> 16.5 KB/block) by processing each wave's 16
// rows as TWO 8-row chunks that reuse one 1032-float wave-private buffer.
// Read-issue pattern is identical to R10 (all 8 f4 loads issued up front,
// before the scan); only the scatter/drain is split. LDS was the occupancy
// cap (4 blocks/CU at 33 KB, VGPR=52 allows more) -> now 8 blocks/CU,
// 39% -> ~78% occupancy, better HBM latency hiding.
// ---------------------------------------------------------------------------
__global__ __launch_bounds__(256) void emb_kernel(const float* __restrict__ x,
                                                  const int* __restrict__ lengths,
                                                  float* __restrict__ out,
                                                  int n_seg, int maxt) {
    __shared__ alignas(16) float lt[4 * 1032];   // 16.5 KB: 8-row buffer per wave
    __shared__ int sw[4];                         // cross-wave scan partials
    __shared__ int sres[4];                       // off, L, tloc, found
    const int tid = threadIdx.x;
    const int lane = tid & 63, wave = tid >> 6;
    const int tau = blockIdx.x;

    if (tau < maxt) {
        if (tid == 0) sres[3] = 0;

        // ---- lengths loads FIRST (chunk 0), so scan waits only on these ----
        int l[8];
        const int i0 = tid * 8;
        if (i0 + 8 <= n_seg) {
            const i4* lp = (const i4*)(lengths + i0);
            const i4 u0 = lp[0], u1 = lp[1];
            l[0] = u0.x; l[1] = u0.y; l[2] = u0.z; l[3] = u0.w;
            l[4] = u1.x; l[5] = u1.y; l[6] = u1.z; l[7] = u1.w;
        } else {
            #pragma unroll
            for (int j = 0; j < 8; ++j) l[j] = (i0 + j < n_seg) ? lengths[i0 + j] : 0;
        }

        // ---- speculative x loads: uniform-mapping guess row = 64*tau ----
        // Same issue pattern as R10 (8 x f4 per lane, back-to-back), split
        // into two named sets so chunk A's scatter waits on only a[].
        f4 a[4], b[4];
        {
            const f4* ga = (const f4*)(x + (size_t)(64 * tau + 16 * wave) * 128);
            #pragma unroll
            for (int p = 0; p < 4; ++p) a[p] = ga[lane + 64 * p];
            #pragma unroll
            for (int p = 0; p < 4; ++p) b[p] = ga[lane + 64 * p + 256];
        }
        __syncthreads();                          // sres[3] init visible

        // ---- chunked block-wide double scan to locate tile tau ----
        int carry_rows = 0, carry_tiles = 0;
        for (int base = 0; base < n_seg; base += 2048) {
            if (base > 0) {                       // later chunks (n_seg > 2048)
                const int ii = base + tid * 8;
                #pragma unroll
                for (int j = 0; j < 8; ++j) l[j] = (ii + j < n_seg) ? lengths[ii + j] : 0;
            }
            const int th_rows = l[0]+l[1]+l[2]+l[3]+l[4]+l[5]+l[6]+l[7];
            int incl = th_rows;
            #pragma unroll
            for (int d = 1; d < 64; d <<= 1) { int u = __shfl_up(incl, d, 64); if (lane >= d) incl += u; }
            if (lane == 63) sw[wave] = incl;
            __syncthreads();
            const int w0 = sw[0], w1 = sw[1], w2 = sw[2], w3 = sw[3];
            __syncthreads();
            const int wbase = (wave > 0 ? w0 : 0) + (wave > 1 ? w1 : 0) + (wave > 2 ? w2 : 0);
            const int rows_total = w0 + w1 + w2 + w3;

            int run = carry_rows + wbase + incl - th_rows;
            int offj[8], f[8]; int th_tiles = 0;
            #pragma unroll
            for (int j = 0; j < 8; ++j) {
                offj[j] = run; run += l[j];
                f[j] = ((offj[j] & 15) == 0) ? (l[j] >> 6) : 0;
                th_tiles += f[j];
            }
            int tincl = th_tiles;
            #pragma unroll
            for (int d = 1; d < 64; d <<= 1) { int u = __shfl_up(tincl, d, 64); if (lane >= d) tincl += u; }
            if (lane == 63) sw[wave] = tincl;
            __syncthreads();
            const int t0 = sw[0], t1 = sw[1], t2 = sw[2], t3 = sw[3];
            __syncthreads();
            const int tbase = (wave > 0 ? t0 : 0) + (wave > 1 ? t1 : 0) + (wave > 2 ? t2 : 0);
            const int tiles_total = t0 + t1 + t2 + t3;

            const int rel = tau - carry_tiles - (tbase + tincl - th_tiles);
            if (rel >= 0 && rel < th_tiles) {
                int cum = 0;
                #pragma unroll
                for (int j = 0; j < 8; ++j) {
                    if (rel >= cum && rel < cum + f[j]) {
                        sres[0] = offj[j]; sres[1] = l[j]; sres[2] = rel - cum; sres[3] = 1;
                    }
                    cum += f[j];
                }
            }
            carry_rows += rows_total; carry_tiles += tiles_total;
            __syncthreads();
            if (sres[3]) break;                   // uniform read-after-sync
        }
        if (!sres[3]) return;                     // tau >= n_tiles: idle
        const int off = sres[0], L = sres[1], tloc = sres[2];

        // ---- verify speculation; reload iff ragged mapping differs ----
        const int gr = off + 64 * tloc;           // actual global start row
        if (gr != 64 * tau) {
            const f4* src2 = (const f4*)(x + (size_t)(gr + 16 * wave) * 128);
            #pragma unroll
            for (int p = 0; p < 4; ++p) a[p] = src2[lane + 64 * p];
            #pragma unroll
            for (int p = 0; p < 4; ++p) b[p] = src2[lane + 64 * p + 256];
        }

        const float invL = 1.0f / (float)L;
        const int r0 = 64 * tloc + 16 * wave;     // segment-relative row
        float* __restrict__ lb = lt + wave * 1032;
        const f4* __restrict__ l4 = (const f4*)lb;

        // ---- chunk A: rows r0 .. r0+7 ----
        #pragma unroll
        for (int p = 0; p < 4; ++p) {
            const int q = lane + 64 * p;          // f4 index in 8x128 chunk
            float* d = &lb[(q >> 5) * 129 + 1 + ((q & 31) << 2)];
            d[0] = a[p].x; d[1] = a[p].y; d[2] = a[p].z; d[3] = a[p].w;
        }
        if (lane < 8) lb[lane * 129] = (float)(r0 + lane + 1) * invL;
        {
            f4* __restrict__ o4 = (f4*)(out + ((size_t)off + r0) * 129);
            #pragma unroll
            for (int p = 0; p < 4; ++p) o4[lane + 64 * p] = l4[lane + 64 * p];
            if (lane < 2) o4[256 + lane] = l4[256 + lane];
        }

        // ---- chunk B: rows r0+8 .. r0+15 (buffer reused; intra-wave DS
        //      ordering on same addresses keeps this hazard-safe) ----
        #pragma unroll
        for (int p = 0; p < 4; ++p) {
            const int q = lane + 64 * p;
            float* d = &lb[(q >> 5) * 129 + 1 + ((q & 31) << 2)];
            d[0] = b[p].x; d[1] = b[p].y; d[2] = b[p].z; d[3] = b[p].w;
        }
        if (lane < 8) lb[lane * 129] = (float)(r0 + 8 + lane + 1) * invL;
        {
            f4* __restrict__ o4 = (f4*)(out + ((size_t)off + r0 + 8) * 129);
            #pragma unroll
            for (int p = 0; p < 4; ++p) o4[lane + 64 * p] = l4[lane + 64 * p];
            if (lane < 2) o4[256 + lane] = l4[256 + lane];
        }
    } else {
        // ---- ragged tail / unaligned-segment fallback (no-op when uniform) ----
        const int s = tau - maxt;
        if (s >= n_seg) return;
        int partial = 0;
        for (int i = tid; i < s; i += 256) partial += lengths[i];
        #pragma unroll
        for (int d = 32; d > 0; d >>= 1) partial += __shfl_xor(partial, d, 64);
        if (lane == 0) sw[wave] = partial;
        __syncthreads();
        const int off = sw[0] + sw[1] + sw[2] + sw[3];
        const int L = lengths[s];
        if (L <= 0) return;
        const float invL = 1.0f / (float)L;
        const float* __restrict__ xs = x + (size_t)off * 128;
        float* __restrict__ os = out + (size_t)off * 129;
        const int f = ((off & 15) == 0) ? (L >> 6) : 0;
        const int E = L * 129;
        for (int e = f * 64 * 129 + tid; e < E; e += 256) {
            const int row = e / 129;
            const int c = e - row * 129;
            os[e] = (c == 0) ? (float)(row + 1) * invL
                             : xs[(size_t)row * 128 + (c - 1)];
        }
    }
}

extern "C" void kernel_launch(void* const* d_in, const int* in_sizes, int n_in,
                              void* d_out, int out_size, void* d_ws, size_t ws_size,
                              hipStream_t stream) {
    const float* x = (const float*)d_in[0];
    const int* lengths = (const int*)d_in[1];
    const int n_seg = in_sizes[1];
    const int rows = in_sizes[0] / 128;
    const int maxt = rows / 64;

    emb_kernel<<<maxt + n_seg, 256, 0, stream>>>(x, lengths, (float*)d_out, n_seg, maxt);
}

// Round 13
// 191.569 us; speedup vs baseline: 1.1237x; 1.0780x over previous
//
#include <hip/hip_runtime.h>

typedef float f4 __attribute__((ext_vector_type(4)));
typedef int i4 __attribute__((ext_vector_type(4)));

// ---------------------------------------------------------------------------
// R13: R10's sequential-front tile kernel (199 us), single change: the
// per-block mapping scan (2 block-wide shfl+LDS scans, ~6 syncthreads) is
// replaced by a WAVE-LOCAL barrier-free scan. Each wave loads all lengths
// (32 segments/lane as 8 x i4), does two 6-step shfl scans + unrolled serial
// walks, and broadcasts the hit via __ballot/__shfl. No barriers, no LDS on
// the fast path -> the 4 waves stream fully independently; mapping latency
// overlaps the speculative x loads instead of rendezvousing behind them.
// ---------------------------------------------------------------------------
__global__ __launch_bounds__(256) void emb_kernel(const float* __restrict__ x,
                                                  const int* __restrict__ lengths,
                                                  float* __restrict__ out,
                                                  int n_seg, int maxt) {
    __shared__ alignas(16) float lt[4 * 2064];   // 33 KB: 16-row buffer per wave
    __shared__ int sw[4];                         // tail branch only
    const int tid = threadIdx.x;
    const int lane = tid & 63, wave = tid >> 6;
    const int tau = blockIdx.x;

    if (tau < maxt) {
        // ---- speculative x loads: uniform-mapping guess row = 64*tau ----
        // Always in-bounds: 64*tau + 63 < 64*maxt <= rows.
        f4 a[8];
        {
            const f4* ga = (const f4*)(x + (size_t)(64 * tau + 16 * wave) * 128);
            #pragma unroll
            for (int p = 0; p < 8; ++p) a[p] = ga[lane + 64 * p];
        }

        // ---- wave-local barrier-free mapping scan (32 segments per lane) ----
        int off = 0, L = 0, tloc = 0, found = 0;
        int carry_rows = 0, carry_tiles = 0;
        for (int base = 0; base < n_seg; base += 2048) {
            const int i0 = base + lane * 32;
            i4 lv[8];
            if (i0 + 32 <= n_seg) {
                const i4* lp = (const i4*)(lengths + i0);
                #pragma unroll
                for (int g = 0; g < 8; ++g) lv[g] = lp[g];
            } else {
                #pragma unroll
                for (int g = 0; g < 8; ++g) {
                    #pragma unroll
                    for (int j = 0; j < 4; ++j) {
                        const int idx = i0 + 4 * g + j;
                        lv[g][j] = (idx < n_seg) ? lengths[idx] : 0;
                    }
                }
            }
            int th_rows = 0;
            #pragma unroll
            for (int g = 0; g < 8; ++g)
                th_rows += lv[g].x + lv[g].y + lv[g].z + lv[g].w;

            int incl = th_rows;                   // inclusive row scan
            #pragma unroll
            for (int d = 1; d < 64; d <<= 1) { int u = __shfl_up(incl, d, 64); if (lane >= d) incl += u; }
            const int rows_total = __shfl(incl, 63, 64);

            // walk 1: count this lane's aligned tiles
            int run = carry_rows + incl - th_rows;
            int th_tiles = 0;
            #pragma unroll
            for (int g = 0; g < 8; ++g) {
                #pragma unroll
                for (int j = 0; j < 4; ++j) {
                    const int len = lv[g][j];
                    th_tiles += ((run & 15) == 0) ? (len >> 6) : 0;
                    run += len;
                }
            }
            int tincl = th_tiles;                 // inclusive tile scan
            #pragma unroll
            for (int d = 1; d < 64; d <<= 1) { int u = __shfl_up(tincl, d, 64); if (lane >= d) tincl += u; }
            const int tiles_total = __shfl(tincl, 63, 64);

            const int rel = tau - (carry_tiles + tincl - th_tiles);
            if (rel >= 0 && rel < th_tiles) {
                // walk 2: locate the segment inside this lane's window
                int run2 = carry_rows + incl - th_rows;
                int cum = 0;
                #pragma unroll
                for (int g = 0; g < 8; ++g) {
                    #pragma unroll
                    for (int j = 0; j < 4; ++j) {
                        const int len = lv[g][j];
                        const int f = ((run2 & 15) == 0) ? (len >> 6) : 0;
                        if (rel >= cum && rel < cum + f) {
                            off = run2; L = len; tloc = rel - cum; found = 1;
                        }
                        cum += f;
                        run2 += len;
                    }
                }
            }
            carry_rows += rows_total;
            carry_tiles += tiles_total;

            const unsigned long long m = __ballot(found);
            if (m) {
                const int src = __ffsll(m) - 1;
                off  = __shfl(off,  src, 64);
                L    = __shfl(L,    src, 64);
                tloc = __shfl(tloc, src, 64);
                found = 1;
                break;
            }
        }
        if (!found) return;                       // tau >= n_tiles: idle

        // ---- verify speculation; reload iff ragged mapping differs ----
        const int gr = off + 64 * tloc;           // actual global start row
        if (gr != 64 * tau) {
            const f4* src2 = (const f4*)(x + (size_t)(gr + 16 * wave) * 128);
            #pragma unroll
            for (int p = 0; p < 8; ++p) a[p] = src2[lane + 64 * p];
        }

        // ---- proven full-line wave-private LDS-bounce body (R10) ----
        const float invL = 1.0f / (float)L;
        const int r0 = 64 * tloc + 16 * wave;     // segment-relative row
        float* __restrict__ lb = lt + wave * 2064;
        #pragma unroll
        for (int p = 0; p < 8; ++p) {
            const int q = lane + 64 * p;          // f4 index in 16x128 tile
            float* d = &lb[(q >> 5) * 129 + 1 + ((q & 31) << 2)];
            d[0] = a[p].x; d[1] = a[p].y; d[2] = a[p].z; d[3] = a[p].w;
        }
        if (lane < 16) lb[lane * 129] = (float)(r0 + lane + 1) * invL;

        const f4* __restrict__ l4 = (const f4*)lb;
        f4* __restrict__ o4 = (f4*)(out + ((size_t)off + r0) * 129);
        #pragma unroll
        for (int p = 0; p < 8; ++p) o4[lane + 64 * p] = l4[lane + 64 * p];
        if (lane < 4) o4[512 + lane] = l4[512 + lane];
    } else {
        // ---- ragged tail / unaligned-segment fallback (no-op when uniform) ----
        const int s = tau - maxt;
        if (s >= n_seg) return;
        int partial = 0;
        for (int i = tid; i < s; i += 256) partial += lengths[i];
        #pragma unroll
        for (int d = 32; d > 0; d >>= 1) partial += __shfl_xor(partial, d, 64);
        if (lane == 0) sw[wave] = partial;
        __syncthreads();
        const int off = sw[0] + sw[1] + sw[2] + sw[3];
        const int L = lengths[s];
        if (L <= 0) return;
        const float invL = 1.0f / (float)L;
        const float* __restrict__ xs = x + (size_t)off * 128;
        float* __restrict__ os = out + (size_t)off * 129;
        const int f = ((off & 15) == 0) ? (L >> 6) : 0;
        const int E = L * 129;
        for (int e = f * 64 * 129 + tid; e < E; e += 256) {
            const int row = e / 129;
            const int c = e - row * 129;
            os[e] = (c == 0) ? (float)(row + 1) * invL
                             : xs[(size_t)row * 128 + (c - 1)];
        }
    }
}

extern "C" void kernel_launch(void* const* d_in, const int* in_sizes, int n_in,
                              void* d_out, int out_size, void* d_ws, size_t ws_size,
                              hipStream_t stream) {
    const float* x = (const float*)d_in[0];
    const int* lengths = (const int*)d_in[1];
    const int n_seg = in_sizes[1];
    const int rows = in_sizes[0] / 128;
    const int maxt = rows / 64;

    emb_kernel<<<maxt + n_seg, 256, 0, stream>>>(x, lengths, (float*)d_out, n_seg, maxt);
}